// Round 3
// baseline (171.819 us; speedup 1.0000x reference)
//
#include <hip/hip_runtime.h>
#include <math.h>

// LDR toep_corner via 5-pass FFT chain, radix-16 registerized FFT (4096 = 16^3).
// out[j,b] = Re ifft( sum_{i,s} Gf_ijs . fft( D . fft( Hf_ijs . Xf_ib ) ) )
// Hf = fft(D.H), Xf = ifft(conj(D).x), Gf = fft(G), D_k = exp(i*pi*k/N).
//
// R3: ssplit=1 (grid 512, 4 ranks/wg) + XCD swizzle (per-XCD L2 footprint ~4MB)
//     + xrow registerized + 2-buffer FFT (2 barriers/FFT instead of 4).

#define NFFT  4096
#define NT    256
#define CIN   4
#define COUT  4
#define RANK  4
#define BATCH 32
#define PI_F  3.14159265358979323846f

__device__ __forceinline__ float2 cmul(float2 a, float2 b) {
    return make_float2(a.x*b.x - a.y*b.y, a.x*b.y + a.y*b.x);
}
__device__ __forceinline__ float2 cadd(float2 a, float2 b){ return make_float2(a.x+b.x, a.y+b.y); }
__device__ __forceinline__ float2 csub(float2 a, float2 b){ return make_float2(a.x-b.x, a.y-b.y); }

// LDS bank swizzle: XOR low 4 index bits with bits 4..7. All access patterns
// (16tid+k writes, tid+256r reads, q+256p+16k writes) hit each bank-pair with
// exactly 4 of 64 lanes = the b64 floor (conflict-free, proven R2: conflicts=0).
__device__ __forceinline__ int SW(int e){ return e ^ ((e >> 4) & 15); }

// 16-point DFT in registers, natural order in/out (proven R2).
template<int SIGN>
__device__ __forceinline__ void dft16(float2 v[16]) {
    const float sgn = (float)SIGN;
    const float C8 = 0.923879532511287f, S8 = 0.382683432365090f, H2 = 0.707106781186548f;
    const float2 w1 = make_float2( C8,  sgn*S8);
    const float2 w2 = make_float2( H2,  sgn*H2);
    const float2 w3 = make_float2( S8,  sgn*C8);
    const float2 w4 = make_float2(0.f,  sgn);
    const float2 w6 = make_float2(-H2,  sgn*H2);
    const float2 w9 = make_float2(-C8, -sgn*S8);
    float2 t[16];
    #pragma unroll
    for (int p = 0; p < 4; ++p) {
        float2 a0 = v[p], a1 = v[p+4], a2 = v[p+8], a3 = v[p+12];
        float2 b0 = cadd(a0,a2), b1 = csub(a0,a2), b2 = cadd(a1,a3), b3 = csub(a1,a3);
        float2 ib3 = make_float2(-sgn*b3.y, sgn*b3.x);   // SIGN*i*b3
        float2 X0 = cadd(b0,b2), X2c = csub(b0,b2);
        float2 X1 = cadd(b1,ib3), X3 = csub(b1,ib3);
        if (p == 1) { X1 = cmul(X1,w1); X2c = cmul(X2c,w2); X3 = cmul(X3,w3); }
        else if (p == 2) { X1 = cmul(X1,w2); X2c = cmul(X2c,w4); X3 = cmul(X3,w6); }
        else if (p == 3) { X1 = cmul(X1,w3); X2c = cmul(X2c,w6); X3 = cmul(X3,w9); }
        t[4*p+0]=X0; t[4*p+1]=X1; t[4*p+2]=X2c; t[4*p+3]=X3;
    }
    #pragma unroll
    for (int q = 0; q < 4; ++q) {
        float2 a0 = t[q], a1 = t[q+4], a2 = t[q+8], a3 = t[q+12];
        float2 b0 = cadd(a0,a2), b1 = csub(a0,a2), b2 = cadd(a1,a3), b3 = csub(a1,a3);
        float2 ib3 = make_float2(-sgn*b3.y, sgn*b3.x);
        v[q+0]  = cadd(b0,b2);
        v[q+8]  = csub(b0,b2);
        v[q+4]  = cadd(b1,ib3);
        v[q+12] = csub(b1,ib3);
    }
}

// v[k] *= e^{i*k*ang}, incremental powers.
__device__ __forceinline__ void twiddle16(float2 v[16], float ang) {
    float sn, cs; __sincosf(ang, &sn, &cs);
    float2 w = make_float2(cs, sn), t = w;
    v[1] = cmul(v[1], t);
    #pragma unroll
    for (int k = 2; k < 16; ++k) { t = cmul(t, w); v[k] = cmul(v[k], t); }
}

// Stockham radix-16, 3 stages, two-buffer ping-pong: only 2 barriers per FFT.
// Input: v[r] = x[tid + 256r]. Output: v[k] = X[tid + 256k]. No exit barrier:
// bufA's last reads precede sync2; bufB's last reads precede the NEXT call's
// sync1 — every rewrite is fenced by one of the two barriers.
template<int SIGN>
__device__ void fft4096_r16(float2 v[16], float2* bufA, float2* bufB, int tid) {
    // Stage A: p=tid, s=1
    dft16<SIGN>(v);
    twiddle16(v, (float)SIGN * 2.0f * PI_F * (float)tid / 4096.0f);
    #pragma unroll
    for (int k = 0; k < 16; ++k) bufA[SW(16*tid + k)] = v[k];
    __syncthreads();
    // Stage B: p=tid>>4, q=tid&15, s=16
    #pragma unroll
    for (int r = 0; r < 16; ++r) v[r] = bufA[SW(tid + 256*r)];
    dft16<SIGN>(v);
    twiddle16(v, (float)SIGN * 2.0f * PI_F * (float)(tid >> 4) / 256.0f);
    {
        const int q = tid & 15, p = tid >> 4;
        #pragma unroll
        for (int k = 0; k < 16; ++k) bufB[SW(q + 256*p + 16*k)] = v[k];
    }
    __syncthreads();
    // Stage C: s=256, no twiddle
    #pragma unroll
    for (int r = 0; r < 16; ++r) v[r] = bufB[SW(tid + 256*r)];
    dft16<SIGN>(v);
}

// ---- Kernel A: precompute Hf (64 rows), Gf (64 rows), Xf (128 rows) ----
__global__ __launch_bounds__(NT, 2) void ldr_pre_k(
    const float* __restrict__ x, const float* __restrict__ G, const float* __restrict__ H,
    float2* __restrict__ Hf, float2* __restrict__ Gf, float2* __restrict__ Xf)
{
    __shared__ float2 ldsA[NFFT];
    __shared__ float2 ldsB[NFFT];
    const int tid = threadIdx.x;
    const int bid = blockIdx.x;
    float2 v[16];
    if (bid < 64) {
        const float* h = H + (size_t)bid * NFFT;
        float sn, cs; __sincosf(PI_F * (float)tid / (float)NFFT, &sn, &cs);
        float2 d = make_float2(cs, sn);
        const float2 dstep = make_float2(0.980785280403230449f, 0.195090322016128268f); // e^{i*pi/16}
        #pragma unroll
        for (int k = 0; k < 16; ++k) {
            float hv = h[tid + 256*k];
            v[k] = make_float2(d.x*hv, d.y*hv);
            d = cmul(d, dstep);
        }
        fft4096_r16<-1>(v, ldsA, ldsB, tid);
        float2* o = Hf + (size_t)bid * NFFT;
        #pragma unroll
        for (int k = 0; k < 16; ++k) o[tid + 256*k] = v[k];
    } else if (bid < 128) {
        const int row = bid - 64;
        const float* g = G + (size_t)row * NFFT;
        #pragma unroll
        for (int k = 0; k < 16; ++k) v[k] = make_float2(g[tid + 256*k], 0.0f);
        fft4096_r16<-1>(v, ldsA, ldsB, tid);
        float2* o = Gf + (size_t)row * NFFT;
        #pragma unroll
        for (int k = 0; k < 16; ++k) o[tid + 256*k] = v[k];
    } else {
        const int row = bid - 128;
        const float* xp = x + (size_t)row * NFFT;
        float sn, cs; __sincosf(PI_F * (float)tid / (float)NFFT, &sn, &cs);
        float2 d = make_float2(cs, -sn);                                                 // conj(D)
        const float2 dstep = make_float2(0.980785280403230449f, -0.195090322016128268f);
        #pragma unroll
        for (int k = 0; k < 16; ++k) {
            float xv = xp[tid + 256*k];
            v[k] = make_float2(d.x*xv, d.y*xv);
            d = cmul(d, dstep);
        }
        fft4096_r16<1>(v, ldsA, ldsB, tid);
        const float invn = 1.0f / (float)NFFT;
        float2* o = Xf + (size_t)row * NFFT;
        #pragma unroll
        for (int k = 0; k < 16; ++k) o[tid + 256*k] = make_float2(v[k].x*invn, v[k].y*invn);
    }
}

// ---- Kernel B: middle, grid 512, all 4 ranks per wg.
// XCD swizzle: physical bid p -> xcd = p&7 (round-robin mapping heuristic),
// ij = (p&7) + 8*((p>>3)&1), b = p>>4.  Each XCD touches 2 ij values:
// Hf/Gf footprint 2 MB + Xf 2 MB = ~4 MB = one XCD's L2.
__global__ __launch_bounds__(NT, 2) void ldr_middle_k(
    const float2* __restrict__ Hf, const float2* __restrict__ Xf,
    const float2* __restrict__ Gf, float2* __restrict__ P)
{
    __shared__ float2 ldsA[NFFT];
    __shared__ float2 ldsB[NFFT];
    const int tid = threadIdx.x;
    const int p   = blockIdx.x;
    const int ij  = (p & 7) + 8 * ((p >> 3) & 1);
    const int b   = p >> 4;
    const int i   = ij >> 2;          // COUT = 4
    const float2* xrow = Xf + (size_t)(i*BATCH + b) * NFFT;

    // xrow registerized: loaded once, reused for all 4 ranks.
    float2 xr[16];
    #pragma unroll
    for (int k = 0; k < 16; ++k) xr[k] = xrow[tid + 256*k];

    float2 acc[16];
    #pragma unroll
    for (int k = 0; k < 16; ++k) acc[k] = make_float2(0.0f, 0.0f);

    for (int s = 0; s < RANK; ++s) {
        const float2* hrow = Hf + (size_t)(ij*RANK + s) * NFFT;
        const float2* grow = Gf + (size_t)(ij*RANK + s) * NFFT;
        float2 v[16];
        #pragma unroll
        for (int k = 0; k < 16; ++k) v[k] = cmul(hrow[tid + 256*k], xr[k]);
        fft4096_r16<-1>(v, ldsA, ldsB, tid);
        // multiply by D in registers: elem e = tid + 256k, D_e = e^{i*pi*e/N}
        float sn, cs; __sincosf(PI_F * (float)tid / (float)NFFT, &sn, &cs);
        float2 d = make_float2(cs, sn);
        const float2 dstep = make_float2(0.980785280403230449f, 0.195090322016128268f);
        #pragma unroll
        for (int k = 0; k < 16; ++k) { v[k] = cmul(v[k], d); d = cmul(d, dstep); }
        fft4096_r16<-1>(v, ldsA, ldsB, tid);
        #pragma unroll
        for (int k = 0; k < 16; ++k)
            acc[k] = cadd(acc[k], cmul(grow[tid + 256*k], v[k]));
    }
    float2* prow = P + (size_t)(ij*BATCH + b) * NFFT;
    #pragma unroll
    for (int k = 0; k < 16; ++k) prow[tid + 256*k] = acc[k];
}

// ---- Kernel C: final. out[j,b] = Re ifft( sum_i P[i,j,b] ) / N ----
__global__ __launch_bounds__(NT, 2) void ldr_final_k(
    const float2* __restrict__ P, float* __restrict__ out)
{
    __shared__ float2 ldsA[NFFT];
    __shared__ float2 ldsB[NFFT];
    const int tid = threadIdx.x;
    const int bid = blockIdx.x;          // j*BATCH + b
    const int b = bid % BATCH;
    const int j = bid / BATCH;
    float2 v[16];
    #pragma unroll
    for (int k = 0; k < 16; ++k) v[k] = make_float2(0.0f, 0.0f);
    #pragma unroll
    for (int i = 0; i < CIN; ++i) {
        const float2* row = P + (size_t)((i*COUT + j)*BATCH + b) * NFFT;
        #pragma unroll
        for (int k = 0; k < 16; ++k) v[k] = cadd(v[k], row[tid + 256*k]);
    }
    fft4096_r16<1>(v, ldsA, ldsB, tid);
    const float invn = 1.0f / (float)NFFT;
    float* orow = out + (size_t)bid * NFFT;
    #pragma unroll
    for (int k = 0; k < 16; ++k) orow[tid + 256*k] = v[k].x * invn;
}

extern "C" void kernel_launch(void* const* d_in, const int* in_sizes, int n_in,
                              void* d_out, int out_size, void* d_ws, size_t ws_size,
                              hipStream_t stream) {
    const float* x = (const float*)d_in[0];   // (CIN, B, N)
    const float* G = (const float*)d_in[1];   // (CIN, COUT, R, N)
    const float* H = (const float*)d_in[2];   // (CIN, COUT, R, N)
    float* out = (float*)d_out;               // (COUT, B, N)

    float2* Hf = (float2*)d_ws;                    // 64 rows  (2 MB)
    float2* Gf = Hf + (size_t)64 * NFFT;           // 64 rows  (2 MB)
    float2* Xf = Gf + (size_t)64 * NFFT;           // 128 rows (4 MB)
    float2* P  = Xf + (size_t)128 * NFFT;          // 512 rows (16 MB)

    ldr_pre_k<<<256, NT, 0, stream>>>(x, G, H, Hf, Gf, Xf);
    ldr_middle_k<<<CIN * COUT * BATCH, NT, 0, stream>>>(Hf, Xf, Gf, P);
    ldr_final_k<<<COUT * BATCH, NT, 0, stream>>>(P, out);
}